// Round 1
// baseline (1000.971 us; speedup 1.0000x reference)
//
#include <hip/hip_runtime.h>

typedef unsigned short u16;
typedef __attribute__((ext_vector_type(8))) short bf16x8;
typedef __attribute__((ext_vector_type(4))) float f32x4;
typedef __attribute__((ext_vector_type(4))) unsigned int u32x4;

__device__ __forceinline__ u16 f2bf(float x){
  unsigned u = __builtin_bit_cast(unsigned, x);
  unsigned r = (u + 0x7FFFu + ((u >> 16) & 1u)) >> 16;   // RNE
  return (u16)r;
}
__device__ __forceinline__ float bf2f(u16 h){
  unsigned u = ((unsigned)h) << 16;
  return __builtin_bit_cast(float, u);
}

__device__ __forceinline__ void gld_lds16(const void* g, void* l){
  __builtin_amdgcn_global_load_lds((const __attribute__((address_space(1))) void*)g,
                                   (__attribute__((address_space(3))) void*)l,
                                   16, 0, 0);
}

// ---------------------------------------------------------------------------
// Weight transpose + bf16 hi/lo split:  W[K][1024] -> WT_hi/WT_lo [1024][Kpad]
// (pad rows k>=K with zeros). 32x32 LDS-tiled transpose, coalesced both sides.
// ---------------------------------------------------------------------------
__global__ void wconv_kernel(const float* __restrict__ W,
                             u16* __restrict__ Th, u16* __restrict__ Tl,
                             int K, int Kpad)
{
  __shared__ float t[32][33];
  int k0 = blockIdx.x * 32;
  int n0 = blockIdx.y * 32;
  int tx = threadIdx.x & 31, ty = threadIdx.x >> 5;   // 256 threads: ty in 0..7
#pragma unroll
  for (int j = 0; j < 4; j++){
    int k = k0 + ty + j*8;
    float v = (k < K) ? W[(size_t)k*1024 + (n0 + tx)] : 0.f;
    t[ty + j*8][tx] = v;
  }
  __syncthreads();
#pragma unroll
  for (int j = 0; j < 4; j++){
    int n = n0 + ty + j*8;
    int k = k0 + tx;
    float v = t[tx][ty + j*8];
    u16 hi = f2bf(v);
    u16 lo = f2bf(v - bf2f(hi));
    size_t idx = (size_t)n*Kpad + k;
    Th[idx] = hi; Tl[idx] = lo;
  }
}

// ---------------------------------------------------------------------------
// feats: x[row,0..8]=Re(z), x[row,9..17]=Im(z). Build the 729 bihom section
// products / kappa, write as bf16 hi/lo, padded to 736 cols with zeros.
// Per block: 8 rows. Coeffs (6 r + 3 i per factor + 1/kappa) staged in LDS to
// keep all indexing off scratch (rule #20).
// ---------------------------------------------------------------------------
__global__ void feats_kernel(const float* __restrict__ x,
                             u16* __restrict__ fh, u16* __restrict__ fl,
                             int row0)
{
  __shared__ float c[8][28];
  const int tid = threadIdx.x;
  const int lrow0 = blockIdx.x * 8;
  if (tid < 8){
    const float* xr = x + (size_t)(row0 + lrow0 + tid) * 18;
    float kk = 1.f;
#pragma unroll
    for (int f = 0; f < 3; f++){
      float xa = xr[3*f+0], xb = xr[3*f+1], xc = xr[3*f+2];
      float ya = xr[9+3*f+0], yb = xr[9+3*f+1], yc = xr[9+3*f+2];
      int bse = f * 9;
      c[tid][bse+0] = xa*xa + ya*ya;     // r[(0,0)]
      c[tid][bse+1] = xa*xb + ya*yb;     // r[(0,1)]
      c[tid][bse+2] = xa*xc + ya*yc;     // r[(0,2)]
      c[tid][bse+3] = xb*xb + yb*yb;     // r[(1,1)]
      c[tid][bse+4] = xb*xc + yb*yc;     // r[(1,2)]
      c[tid][bse+5] = xc*xc + yc*yc;     // r[(2,2)]
      c[tid][bse+6] = xa*yb - xb*ya;     // i[(0,1)]
      c[tid][bse+7] = xa*yc - xc*ya;     // i[(0,2)]
      c[tid][bse+8] = xb*yc - xc*yb;     // i[(1,2)]
      kk *= (xa*xa+ya*ya + xb*xb+yb*yb + xc*xc+yc*yc);
    }
    c[tid][27] = 1.f / kk;
  }
  __syncthreads();
  // coefficient layout per row: r0:0..5  i0:6..8  r1:9..14  i1:15..17
  //                             r2:18..23 i2:24..26  invk:27
#pragma unroll 1
  for (int jj = 0; jj < 23; jj++){               // 8 rows * 736 = 5888 = 23*256
    int idx = jj * 256 + tid;
    int rl = idx / 736;
    int o  = idx - rl * 736;
    const float* cc = c[rl];
    float v = 0.f;
    if (o < 729){
      int i12, j; float sgn; bool useR, jr2;
      if (o < 270)      { i12 = o/6;            j = o - i12*6;        sgn =  1.f; useR = true;  jr2 = true;  }
      else if (o < 378) { int t = o-270; i12 = t/3; j = t - i12*3;    sgn = -1.f; useR = false; jr2 = false; }
      else if (o < 513) { int t = o-378; i12 = t/3; j = t - i12*3;    sgn =  1.f; useR = true;  jr2 = false; }
      else              { int t = o-513; i12 = t/6; j = t - i12*6;    sgn = -1.f; useR = false; jr2 = true;  }
      float v12;
      if (useR){   // it_r45[i12]
        if (i12 < 36) v12 = cc[i12/6] * cc[9 + i12%6];
        else { int u = i12 - 36; v12 = -(cc[6 + u/3] * cc[15 + u%3]); }
      } else {     // it_i36[i12]
        if (i12 < 18) v12 = cc[i12/3] * cc[15 + i12%3];
        else { int u = i12 - 18; v12 = -(cc[6 + u/6] * cc[9 + u%6]); }
      }
      float f2 = jr2 ? cc[18 + j] : cc[24 + j];
      v = sgn * v12 * f2 * cc[27];
    }
    u16 hi = f2bf(v);
    u16 lo = f2bf(v - bf2f(hi));
    size_t oi = (size_t)lrow0 * 736 + idx;
    fh[oi] = hi; fl[oi] = lo;
  }
}

// ---------------------------------------------------------------------------
// GEMM + (x+bias)^2 epilogue, bf16x2 split precision (3 MFMA passes):
//   C = Ahi*Bhi + Alo*Bhi + Ahi*Blo       (A: [M][K] acts, B: WT [1024][K])
// 128x128 tile, BK=32, 4 waves (2x2), 4x4 16x16x32 frags per wave.
// global_load_lds staging into linear LDS [128][32] with XOR slot swizzle
// applied on the global SOURCE address and on the ds_read (rule 21):
//   f(row) = (row>>1)&3 ; 16B slot s stores global slot s^f(row).
// Output written as bf16 hi/lo pair (feeds next layer's staging).
// ---------------------------------------------------------------------------
__global__ __launch_bounds__(256, 2) void gemm_sq(
    const u16* __restrict__ Ahi, const u16* __restrict__ Alo,
    const u16* __restrict__ Bhi, const u16* __restrict__ Blo,
    const float* __restrict__ bias,
    u16* __restrict__ Ohi, u16* __restrict__ Olo,
    int K)
{
  __shared__ __align__(16) u16 lds[4][128][32];   // 0:Ahi 1:Alo 2:Bhi 3:Blo

  const int nb = blockIdx.x;          // 8 col-blocks (N=1024)
  const int mb = blockIdx.y;
  const int tid = threadIdx.x;
  const int wave = tid >> 6, lane = tid & 63;
  const int wm = wave >> 1, wn = wave & 1;

  // ---- staging addressing (per wave: 2 chunks of 16 rows per tile) ----
  const int l4 = lane >> 2, ls = lane & 3;
  const int fsw  = (l4 >> 1) & 3;                  // (row>>1)&3, row=br+l4, br%16==0
  const int koff = ((ls ^ fsw) << 3);              // element offset of source slot
  const int br0 = wave * 32, br1 = wave * 32 + 16;

  const u16* gAh0 = Ahi + (size_t)(mb*128 + br0 + l4) * K + koff;
  const u16* gAh1 = Ahi + (size_t)(mb*128 + br1 + l4) * K + koff;
  const u16* gAl0 = Alo + (size_t)(mb*128 + br0 + l4) * K + koff;
  const u16* gAl1 = Alo + (size_t)(mb*128 + br1 + l4) * K + koff;
  const u16* gBh0 = Bhi + (size_t)(nb*128 + br0 + l4) * K + koff;
  const u16* gBh1 = Bhi + (size_t)(nb*128 + br1 + l4) * K + koff;
  const u16* gBl0 = Blo + (size_t)(nb*128 + br0 + l4) * K + koff;
  const u16* gBl1 = Blo + (size_t)(nb*128 + br1 + l4) * K + koff;

  u16* dAh0 = &lds[0][br0][0]; u16* dAh1 = &lds[0][br1][0];
  u16* dAl0 = &lds[1][br0][0]; u16* dAl1 = &lds[1][br1][0];
  u16* dBh0 = &lds[2][br0][0]; u16* dBh1 = &lds[2][br1][0];
  u16* dBl0 = &lds[3][br0][0]; u16* dBl1 = &lds[3][br1][0];

  // ---- fragment addressing ----
  const int r16 = lane & 15, g = lane >> 4;
  const int fr   = (r16 >> 1) & 3;
  const int slot = ((g ^ fr) << 3);                // element offset of ds_read
  const int rA = wm * 64 + r16;
  const int rB = wn * 64 + r16;

  f32x4 acc[4][4];
#pragma unroll
  for (int m = 0; m < 4; m++)
#pragma unroll
    for (int n = 0; n < 4; n++)
      acc[m][n] = (f32x4){0.f, 0.f, 0.f, 0.f};

  for (int kt = 0; kt < K; kt += 32){
    gld_lds16(gAh0, dAh0); gld_lds16(gAh1, dAh1);
    gld_lds16(gAl0, dAl0); gld_lds16(gAl1, dAl1);
    gld_lds16(gBh0, dBh0); gld_lds16(gBh1, dBh1);
    gld_lds16(gBl0, dBl0); gld_lds16(gBl1, dBl1);
    gAh0 += 32; gAh1 += 32; gAl0 += 32; gAl1 += 32;
    gBh0 += 32; gBh1 += 32; gBl0 += 32; gBl1 += 32;
    __syncthreads();

    bf16x8 ah[4], bh[4];
#pragma unroll
    for (int m = 0; m < 4; m++) ah[m] = *(const bf16x8*)&lds[0][rA + m*16][slot];
#pragma unroll
    for (int n = 0; n < 4; n++) bh[n] = *(const bf16x8*)&lds[2][rB + n*16][slot];
#pragma unroll
    for (int m = 0; m < 4; m++)
#pragma unroll
      for (int n = 0; n < 4; n++)
        acc[m][n] = __builtin_amdgcn_mfma_f32_16x16x32_bf16(ah[m], bh[n], acc[m][n], 0, 0, 0);

    bf16x8 al[4];
#pragma unroll
    for (int m = 0; m < 4; m++) al[m] = *(const bf16x8*)&lds[1][rA + m*16][slot];
#pragma unroll
    for (int m = 0; m < 4; m++)
#pragma unroll
      for (int n = 0; n < 4; n++)
        acc[m][n] = __builtin_amdgcn_mfma_f32_16x16x32_bf16(al[m], bh[n], acc[m][n], 0, 0, 0);

    bf16x8 bl[4];
#pragma unroll
    for (int n = 0; n < 4; n++) bl[n] = *(const bf16x8*)&lds[3][rB + n*16][slot];
#pragma unroll
    for (int m = 0; m < 4; m++)
#pragma unroll
      for (int n = 0; n < 4; n++)
        acc[m][n] = __builtin_amdgcn_mfma_f32_16x16x32_bf16(ah[m], bl[n], acc[m][n], 0, 0, 0);

    __syncthreads();
  }

  // ---- epilogue: (acc + bias)^2 -> bf16 hi/lo ----
#pragma unroll
  for (int n = 0; n < 4; n++){
    int col = nb*128 + wn*64 + n*16 + r16;
    float bv = bias[col];
#pragma unroll
    for (int m = 0; m < 4; m++){
      int rbase = mb*128 + wm*64 + m*16 + g*4;
#pragma unroll
      for (int q = 0; q < 4; q++){
        float val = acc[m][n][q] + bv;
        val = val * val;
        u16 hi = f2bf(val);
        u16 lo = f2bf(val - bf2f(hi));
        size_t oi = (size_t)(rbase + q) * 1024 + col;
        Ohi[oi] = hi; Olo[oi] = lo;
      }
    }
  }
}

// ---------------------------------------------------------------------------
// Layer 3: per-row dot(h2, W3)+b3 -> t = 2*log|a3|*Wf.
// phase 0: stash[row] = t   (tower a)
// phase 1: out[row] = clip(stash[row] - t, +-1e6)   (tower b)
// One wave per row, 4 rows per 256-thread block.
// ---------------------------------------------------------------------------
__global__ void dot3_kernel(const u16* __restrict__ Hh, const u16* __restrict__ Hl,
                            const float* __restrict__ W3, const float* __restrict__ b3,
                            const float* __restrict__ Wf,
                            float* __restrict__ stash, float* __restrict__ out,
                            int row0, int phase)
{
  int r = blockIdx.x * 4 + (threadIdx.x >> 6);
  int lane = threadIdx.x & 63;
  const u32x4* ph = (const u32x4*)(Hh + (size_t)r * 1024 + lane * 16);
  const u32x4* pl = (const u32x4*)(Hl + (size_t)r * 1024 + lane * 16);
  const f32x4* pw = (const f32x4*)(W3 + lane * 16);
  u32x4 vh[2] = { ph[0], ph[1] };
  u32x4 vl[2] = { pl[0], pl[1] };
  f32x4 w[4]  = { pw[0], pw[1], pw[2], pw[3] };
  float s = 0.f;
#pragma unroll
  for (int q = 0; q < 2; q++){
#pragma unroll
    for (int i = 0; i < 4; i++){
      unsigned uh = vh[q][i], ul = vl[q][i];
      float e0 = __builtin_bit_cast(float, uh << 16) +
                 __builtin_bit_cast(float, ul << 16);
      float e1 = __builtin_bit_cast(float, uh & 0xFFFF0000u) +
                 __builtin_bit_cast(float, ul & 0xFFFF0000u);
      int k = q*8 + i*2;
      s += e0 * w[k>>2][k&3] + e1 * w[(k+1)>>2][(k+1)&3];
    }
  }
#pragma unroll
  for (int d = 1; d < 64; d <<= 1) s += __shfl_xor(s, d);
  if (lane == 0){
    float a3 = s + b3[0];
    float t = 2.f * logf(fabsf(a3)) * Wf[0];
    if (phase == 0){
      stash[row0 + r] = t;
    } else {
      float o = stash[row0 + r] - t;
      o = fminf(fmaxf(o, -1000000.f), 1000000.f);
      out[row0 + r] = o;
    }
  }
}

// ---------------------------------------------------------------------------
static inline size_t align256(size_t v){ return (v + 255) & ~(size_t)255; }

extern "C" void kernel_launch(void* const* d_in, const int* in_sizes, int n_in,
                              void* d_out, int out_size, void* d_ws, size_t ws_size,
                              hipStream_t stream)
{
  (void)n_in; (void)out_size;
  const float* x   = (const float*)d_in[0];
  const float* W1a = (const float*)d_in[1];
  const float* b1a = (const float*)d_in[2];
  const float* W2a = (const float*)d_in[3];
  const float* b2a = (const float*)d_in[4];
  const float* W3a = (const float*)d_in[5];
  const float* b3a = (const float*)d_in[6];
  const float* Wfa = (const float*)d_in[7];
  const float* W1b = (const float*)d_in[8];
  const float* b1b = (const float*)d_in[9];
  const float* W2b = (const float*)d_in[10];
  const float* b2b = (const float*)d_in[11];
  const float* W3b = (const float*)d_in[12];
  const float* b3b = (const float*)d_in[13];
  const float* Wfb = (const float*)d_in[14];
  float* out = (float*)d_out;

  const int B  = in_sizes[0] / 18;
  const int K1 = 736;            // 729 padded to 23*32
  const int K2 = 1024;

  char* base = (char*)d_ws;
  size_t off = 0;
  auto carve = [&](size_t bytes) -> char* {
    off = align256(off);
    char* p = base + off;
    off += bytes;
    return p;
  };

  u16* wt1ah = (u16*)carve((size_t)1024 * K1 * 2);
  u16* wt1al = (u16*)carve((size_t)1024 * K1 * 2);
  u16* wt2ah = (u16*)carve((size_t)1024 * K2 * 2);
  u16* wt2al = (u16*)carve((size_t)1024 * K2 * 2);
  u16* wt1bh = (u16*)carve((size_t)1024 * K1 * 2);
  u16* wt1bl = (u16*)carve((size_t)1024 * K1 * 2);
  u16* wt2bh = (u16*)carve((size_t)1024 * K2 * 2);
  u16* wt2bl = (u16*)carve((size_t)1024 * K2 * 2);
  float* stash = (float*)carve((size_t)B * 4);

  size_t fixed = align256(off);
  const long long per_row = (long long)K1*4 + 4096 + 4096;   // feats + h1 + h2 (hi+lo bf16)
  long long avail = (long long)ws_size - (long long)fixed - 4096;
  long long rmax = avail > 0 ? avail / per_row : 0;
  int R = (int)((rmax / 128) * 128);
  if (R > B) R = B;
  if (R < 128) R = 128;   // assume ws is at least ~16 MB

  u16* fh  = (u16*)carve((size_t)R * K1 * 2);
  u16* fl  = (u16*)carve((size_t)R * K1 * 2);
  u16* h1h = (u16*)carve((size_t)R * 1024 * 2);
  u16* h1l = (u16*)carve((size_t)R * 1024 * 2);
  u16* h2h = (u16*)carve((size_t)R * 1024 * 2);
  u16* h2l = (u16*)carve((size_t)R * 1024 * 2);

  // weight transpose + split (runs every call; ~28 MB of coalesced traffic)
  wconv_kernel<<<dim3(K1/32, 32), 256, 0, stream>>>(W1a, wt1ah, wt1al, 729,  K1);
  wconv_kernel<<<dim3(K2/32, 32), 256, 0, stream>>>(W2a, wt2ah, wt2al, 1024, K2);
  wconv_kernel<<<dim3(K1/32, 32), 256, 0, stream>>>(W1b, wt1bh, wt1bl, 729,  K1);
  wconv_kernel<<<dim3(K2/32, 32), 256, 0, stream>>>(W2b, wt2bh, wt2bl, 1024, K2);

  for (int row0 = 0; row0 < B; row0 += R){
    int Rc = B - row0; if (Rc > R) Rc = R;
    feats_kernel<<<Rc/8, 256, 0, stream>>>(x, fh, fl, row0);
    dim3 gg(8, Rc/128);
    gemm_sq<<<gg, 256, 0, stream>>>(fh,  fl,  wt1ah, wt1al, b1a, h1h, h1l, K1);
    gemm_sq<<<gg, 256, 0, stream>>>(h1h, h1l, wt2ah, wt2al, b2a, h2h, h2l, K2);
    dot3_kernel<<<Rc/4, 256, 0, stream>>>(h2h, h2l, W3a, b3a, Wfa, stash, out, row0, 0);
    gemm_sq<<<gg, 256, 0, stream>>>(fh,  fl,  wt1bh, wt1bl, b1b, h1h, h1l, K1);
    gemm_sq<<<gg, 256, 0, stream>>>(h1h, h1l, wt2bh, wt2bl, b2b, h2h, h2l, K2);
    dot3_kernel<<<Rc/4, 256, 0, stream>>>(h2h, h2l, W3b, b3b, Wfb, stash, out, row0, 1);
  }
}

// Round 2
// 790.581 us; speedup vs baseline: 1.2661x; 1.2661x over previous
//
#include <hip/hip_runtime.h>

typedef unsigned short u16;
typedef __attribute__((ext_vector_type(8))) short bf16x8;
typedef __attribute__((ext_vector_type(4))) float f32x4;

__device__ __forceinline__ u16 f2bf(float x){
  unsigned u = __builtin_bit_cast(unsigned, x);
  unsigned r = (u + 0x7FFFu + ((u >> 16) & 1u)) >> 16;   // RNE
  return (u16)r;
}
__device__ __forceinline__ float bf2f(u16 h){
  unsigned u = ((unsigned)h) << 16;
  return __builtin_bit_cast(float, u);
}

__device__ __forceinline__ void gld_lds16(const void* g, void* l){
  __builtin_amdgcn_global_load_lds((const __attribute__((address_space(1))) void*)g,
                                   (__attribute__((address_space(3))) void*)l,
                                   16, 0, 0);
}

// ---------------------------------------------------------------------------
// Weight transpose + bf16 hi/lo split:  W[K][1024] -> WT_hi/WT_lo [1024][Kpad]
// ---------------------------------------------------------------------------
__global__ void wconv_kernel(const float* __restrict__ W,
                             u16* __restrict__ Th, u16* __restrict__ Tl,
                             int K, int Kpad)
{
  __shared__ float t[32][33];
  int k0 = blockIdx.x * 32;
  int n0 = blockIdx.y * 32;
  int tx = threadIdx.x & 31, ty = threadIdx.x >> 5;
#pragma unroll
  for (int j = 0; j < 4; j++){
    int k = k0 + ty + j*8;
    float v = (k < K) ? W[(size_t)k*1024 + (n0 + tx)] : 0.f;
    t[ty + j*8][tx] = v;
  }
  __syncthreads();
#pragma unroll
  for (int j = 0; j < 4; j++){
    int n = n0 + ty + j*8;
    int k = k0 + tx;
    float v = t[tx][ty + j*8];
    u16 hi = f2bf(v);
    u16 lo = f2bf(v - bf2f(hi));
    size_t idx = (size_t)n*Kpad + k;
    Th[idx] = hi; Tl[idx] = lo;
  }
}

// ---------------------------------------------------------------------------
// feats: 729 bihom section products / kappa -> bf16 hi/lo, padded to 768.
// ---------------------------------------------------------------------------
__global__ void feats_kernel(const float* __restrict__ x,
                             u16* __restrict__ fh, u16* __restrict__ fl,
                             int row0)
{
  __shared__ float c[8][28];
  const int tid = threadIdx.x;
  const int lrow0 = blockIdx.x * 8;
  if (tid < 8){
    const float* xr = x + (size_t)(row0 + lrow0 + tid) * 18;
    float kk = 1.f;
#pragma unroll
    for (int f = 0; f < 3; f++){
      float xa = xr[3*f+0], xb = xr[3*f+1], xc = xr[3*f+2];
      float ya = xr[9+3*f+0], yb = xr[9+3*f+1], yc = xr[9+3*f+2];
      int bse = f * 9;
      c[tid][bse+0] = xa*xa + ya*ya;
      c[tid][bse+1] = xa*xb + ya*yb;
      c[tid][bse+2] = xa*xc + ya*yc;
      c[tid][bse+3] = xb*xb + yb*yb;
      c[tid][bse+4] = xb*xc + yb*yc;
      c[tid][bse+5] = xc*xc + yc*yc;
      c[tid][bse+6] = xa*yb - xb*ya;
      c[tid][bse+7] = xa*yc - xc*ya;
      c[tid][bse+8] = xb*yc - xc*yb;
      kk *= (xa*xa+ya*ya + xb*xb+yb*yb + xc*xc+yc*yc);
    }
    c[tid][27] = 1.f / kk;
  }
  __syncthreads();
#pragma unroll 1
  for (int jj = 0; jj < 24; jj++){               // 8 rows * 768 = 6144 = 24*256
    int idx = jj * 256 + tid;
    int rl = idx / 768;
    int o  = idx - rl * 768;
    const float* cc = c[rl];
    float v = 0.f;
    if (o < 729){
      int i12, j; float sgn; bool useR, jr2;
      if (o < 270)      { i12 = o/6;            j = o - i12*6;        sgn =  1.f; useR = true;  jr2 = true;  }
      else if (o < 378) { int t = o-270; i12 = t/3; j = t - i12*3;    sgn = -1.f; useR = false; jr2 = false; }
      else if (o < 513) { int t = o-378; i12 = t/3; j = t - i12*3;    sgn =  1.f; useR = true;  jr2 = false; }
      else              { int t = o-513; i12 = t/6; j = t - i12*6;    sgn = -1.f; useR = false; jr2 = true;  }
      float v12;
      if (useR){
        if (i12 < 36) v12 = cc[i12/6] * cc[9 + i12%6];
        else { int u = i12 - 36; v12 = -(cc[6 + u/3] * cc[15 + u%3]); }
      } else {
        if (i12 < 18) v12 = cc[i12/3] * cc[15 + i12%3];
        else { int u = i12 - 18; v12 = -(cc[6 + u/6] * cc[9 + u%6]); }
      }
      float f2 = jr2 ? cc[18 + j] : cc[24 + j];
      v = sgn * v12 * f2 * cc[27];
    }
    u16 hi = f2bf(v);
    u16 lo = f2bf(v - bf2f(hi));
    size_t oi = (size_t)lrow0 * 768 + idx;
    fh[oi] = hi; fl[oi] = lo;
  }
}

// ---------------------------------------------------------------------------
// Dual-tower GEMM, bf16x2 split precision (3 passes), 128x128 tile, BK=32,
// 2-phase double-buffered LDS (T3 minimum recipe), XCD-swizzled 1D grid.
// nb 0..7 -> tower a cols, nb 8..15 -> tower b cols.
// MODE 0: epilogue (acc+bias)^2 -> Ohi/Olo bf16 pair  (layer 1)
// MODE 1: epilogue (acc+bias)^2 * W3[col], reduce over block cols ->
//         partial[cnb][row]  (layer 2 + dot3 fusion)
// ---------------------------------------------------------------------------
#define STAGE(B) do{ \
    gld_lds16(gAh0, &lds[B][0][br0][0]); gld_lds16(gAh1, &lds[B][0][br1][0]); \
    gld_lds16(gAl0, &lds[B][1][br0][0]); gld_lds16(gAl1, &lds[B][1][br1][0]); \
    gld_lds16(gBh0, &lds[B][2][br0][0]); gld_lds16(gBh1, &lds[B][2][br1][0]); \
    gld_lds16(gBl0, &lds[B][3][br0][0]); gld_lds16(gBl1, &lds[B][3][br1][0]); \
    gAh0 += 32; gAh1 += 32; gAl0 += 32; gAl1 += 32; \
    gBh0 += 32; gBh1 += 32; gBl0 += 32; gBl1 += 32; \
  }while(0)

#define COMPUTE(B) do{ \
    bf16x8 ah_[4], bh_[4], al_[4], bl_[4]; \
    _Pragma("unroll") for (int m_ = 0; m_ < 4; m_++) ah_[m_] = *(const bf16x8*)&lds[B][0][rA + m_*16][slot]; \
    _Pragma("unroll") for (int n_ = 0; n_ < 4; n_++) bh_[n_] = *(const bf16x8*)&lds[B][2][rB + n_*16][slot]; \
    _Pragma("unroll") for (int m_ = 0; m_ < 4; m_++) \
      _Pragma("unroll") for (int n_ = 0; n_ < 4; n_++) \
        acc[m_][n_] = __builtin_amdgcn_mfma_f32_16x16x32_bf16(ah_[m_], bh_[n_], acc[m_][n_], 0, 0, 0); \
    _Pragma("unroll") for (int m_ = 0; m_ < 4; m_++) al_[m_] = *(const bf16x8*)&lds[B][1][rA + m_*16][slot]; \
    _Pragma("unroll") for (int m_ = 0; m_ < 4; m_++) \
      _Pragma("unroll") for (int n_ = 0; n_ < 4; n_++) \
        acc[m_][n_] = __builtin_amdgcn_mfma_f32_16x16x32_bf16(al_[m_], bh_[n_], acc[m_][n_], 0, 0, 0); \
    _Pragma("unroll") for (int n_ = 0; n_ < 4; n_++) bl_[n_] = *(const bf16x8*)&lds[B][3][rB + n_*16][slot]; \
    _Pragma("unroll") for (int m_ = 0; m_ < 4; m_++) \
      _Pragma("unroll") for (int n_ = 0; n_ < 4; n_++) \
        acc[m_][n_] = __builtin_amdgcn_mfma_f32_16x16x32_bf16(ah_[m_], bl_[n_], acc[m_][n_], 0, 0, 0); \
  }while(0)

template<int MODE>
__global__ __launch_bounds__(256, 2) void gemm_k(
    const u16* __restrict__ Aha, const u16* __restrict__ Ala,
    const u16* __restrict__ Ahb, const u16* __restrict__ Alb,
    const u16* __restrict__ Bha, const u16* __restrict__ Bla,
    const u16* __restrict__ Bhb, const u16* __restrict__ Blb,
    const float* __restrict__ biasa, const float* __restrict__ biasb,
    u16* __restrict__ Oha, u16* __restrict__ Ola,
    u16* __restrict__ Ohb, u16* __restrict__ Olb,
    const float* __restrict__ W3a_, const float* __restrict__ W3b_,
    float* __restrict__ Pa, float* __restrict__ Pb, int Pstride,
    int K)
{
  __shared__ __align__(16) u16 lds[2][4][128][32];   // double-buffered
  __shared__ float rowsum[2][128];

  // bijective XCD swizzle (nwg % 8 == 0 always: nwg = 16*MB)
  const int nwg = gridDim.x;
  const int qq = nwg >> 3;
  const int wg = (blockIdx.x & 7) * qq + (blockIdx.x >> 3);
  const int nb = wg & 15;           // nb fast within XCD -> same-mb blocks colocate
  const int mb = wg >> 4;
  const int tower = nb >> 3, cnb = nb & 7;

  const u16* Ahi = tower ? Ahb : Aha;
  const u16* Alo = tower ? Alb : Ala;
  const u16* Bhi = tower ? Bhb : Bha;
  const u16* Blo = tower ? Blb : Bla;
  const float* bias = tower ? biasb : biasa;

  const int tid = threadIdx.x;
  const int wave = tid >> 6, lane = tid & 63;
  const int wm = wave >> 1, wn = wave & 1;

  // staging addressing (rule-21 pair: swizzled global source, linear LDS dest)
  const int l4 = lane >> 2, ls = lane & 3;
  const int fsw  = (l4 >> 1) & 3;
  const int koff = ((ls ^ fsw) << 3);
  const int br0 = wave * 32, br1 = wave * 32 + 16;

  const u16* gAh0 = Ahi + (size_t)(mb*128 + br0 + l4) * K + koff;
  const u16* gAh1 = Ahi + (size_t)(mb*128 + br1 + l4) * K + koff;
  const u16* gAl0 = Alo + (size_t)(mb*128 + br0 + l4) * K + koff;
  const u16* gAl1 = Alo + (size_t)(mb*128 + br1 + l4) * K + koff;
  const u16* gBh0 = Bhi + (size_t)(cnb*128 + br0 + l4) * K + koff;
  const u16* gBh1 = Bhi + (size_t)(cnb*128 + br1 + l4) * K + koff;
  const u16* gBl0 = Blo + (size_t)(cnb*128 + br0 + l4) * K + koff;
  const u16* gBl1 = Blo + (size_t)(cnb*128 + br1 + l4) * K + koff;

  // fragment addressing (swizzled ds_read)
  const int r16 = lane & 15, g = lane >> 4;
  const int fr   = (r16 >> 1) & 3;
  const int slot = ((g ^ fr) << 3);
  const int rA = wm * 64 + r16;
  const int rB = wn * 64 + r16;

  f32x4 acc[4][4];
#pragma unroll
  for (int m = 0; m < 4; m++)
#pragma unroll
    for (int n = 0; n < 4; n++)
      acc[m][n] = (f32x4){0.f, 0.f, 0.f, 0.f};

  // prologue: stage k=0 into buf0
  STAGE(0);
  __syncthreads();

  // 2-phase main loop: K % 64 == 0 (768 or 1024)
#pragma unroll 1
  for (int kt = 0; kt < K; kt += 64){
    STAGE(1);                       // prefetch kt+32 while computing kt
    COMPUTE(0);
    __syncthreads();
    if (kt + 64 < K){ STAGE(0); }   // prefetch kt+64 while computing kt+32
    COMPUTE(1);
    __syncthreads();
  }

  if constexpr (MODE == 0){
    u16* Oh = tower ? Ohb : Oha;
    u16* Ol = tower ? Olb : Ola;
#pragma unroll
    for (int n = 0; n < 4; n++){
      int col = cnb*128 + wn*64 + n*16 + r16;
      float bv = bias[col];
#pragma unroll
      for (int m = 0; m < 4; m++){
        int rbase = mb*128 + wm*64 + m*16 + g*4;
#pragma unroll
        for (int q = 0; q < 4; q++){
          float val = acc[m][n][q] + bv;
          val = val * val;
          u16 hi = f2bf(val);
          u16 lo = f2bf(val - bf2f(hi));
          size_t oi = (size_t)(rbase + q) * 1024 + col;
          Oh[oi] = hi; Ol[oi] = lo;
        }
      }
    }
  } else {
    const float* W3 = tower ? W3b_ : W3a_;
    float w3v[4], bv[4];
#pragma unroll
    for (int n = 0; n < 4; n++){
      int col = cnb*128 + wn*64 + n*16 + r16;
      w3v[n] = W3[col];
      bv[n]  = bias[col];
    }
    float rp[4][4];
#pragma unroll
    for (int m = 0; m < 4; m++)
#pragma unroll
      for (int q = 0; q < 4; q++)
        rp[m][q] = 0.f;
#pragma unroll
    for (int m = 0; m < 4; m++)
#pragma unroll
      for (int n = 0; n < 4; n++)
#pragma unroll
        for (int q = 0; q < 4; q++){
          float v = acc[m][n][q] + bv[n];
          rp[m][q] += v * v * w3v[n];
        }
    // reduce over the 16 column-lanes (r16 = lane bits 0..3)
#pragma unroll
    for (int m = 0; m < 4; m++)
#pragma unroll
      for (int q = 0; q < 4; q++){
        float s = rp[m][q];
        s += __shfl_xor(s, 1); s += __shfl_xor(s, 2);
        s += __shfl_xor(s, 4); s += __shfl_xor(s, 8);
        rp[m][q] = s;
      }
    if (r16 == 0){
#pragma unroll
      for (int m = 0; m < 4; m++)
#pragma unroll
        for (int q = 0; q < 4; q++)
          rowsum[wn][wm*64 + m*16 + g*4 + q] = rp[m][q];
    }
    __syncthreads();
    if (tid < 128){
      float s = rowsum[0][tid] + rowsum[1][tid];
      float* P = tower ? Pb : Pa;
      P[(size_t)cnb * Pstride + mb*128 + tid] = s;
    }
  }
}

// ---------------------------------------------------------------------------
// finalize: a3 = b3 + sum_j partial[j][row]; out = clip(2log|a3a|*Wfa - ..b..)
// ---------------------------------------------------------------------------
__global__ void finalize_kernel(const float* __restrict__ Pa, const float* __restrict__ Pb,
                                int Pstride,
                                const float* __restrict__ b3a, const float* __restrict__ Wfa,
                                const float* __restrict__ b3b, const float* __restrict__ Wfb,
                                float* __restrict__ out, int row0, int Rc)
{
  int r = blockIdx.x * 256 + threadIdx.x;
  if (r >= Rc) return;
  float sa = b3a[0], sb = b3b[0];
#pragma unroll
  for (int j = 0; j < 8; j++){
    sa += Pa[(size_t)j * Pstride + r];
    sb += Pb[(size_t)j * Pstride + r];
  }
  float ta = 2.f * logf(fabsf(sa)) * Wfa[0];
  float tb = 2.f * logf(fabsf(sb)) * Wfb[0];
  float o = ta - tb;
  o = fminf(fmaxf(o, -1000000.f), 1000000.f);
  out[row0 + r] = o;
}

// ---------------------------------------------------------------------------
static inline size_t align256(size_t v){ return (v + 255) & ~(size_t)255; }

extern "C" void kernel_launch(void* const* d_in, const int* in_sizes, int n_in,
                              void* d_out, int out_size, void* d_ws, size_t ws_size,
                              hipStream_t stream)
{
  (void)n_in; (void)out_size;
  const float* x   = (const float*)d_in[0];
  const float* W1a = (const float*)d_in[1];
  const float* b1a = (const float*)d_in[2];
  const float* W2a = (const float*)d_in[3];
  const float* b2a = (const float*)d_in[4];
  const float* W3a = (const float*)d_in[5];
  const float* b3a = (const float*)d_in[6];
  const float* Wfa = (const float*)d_in[7];
  const float* W1b = (const float*)d_in[8];
  const float* b1b = (const float*)d_in[9];
  const float* W2b = (const float*)d_in[10];
  const float* b2b = (const float*)d_in[11];
  const float* W3b = (const float*)d_in[12];
  const float* b3b = (const float*)d_in[13];
  const float* Wfb = (const float*)d_in[14];
  float* out = (float*)d_out;

  const int B  = in_sizes[0] / 18;
  const int K1 = 768;            // 729 padded to 24*32 (even 2-phase step count)
  const int K2 = 1024;

  char* base = (char*)d_ws;
  size_t off = 0;
  auto carve = [&](size_t bytes) -> char* {
    off = align256(off);
    char* p = base + off;
    off += bytes;
    return p;
  };

  u16* wt1ah = (u16*)carve((size_t)1024 * K1 * 2);
  u16* wt1al = (u16*)carve((size_t)1024 * K1 * 2);
  u16* wt2ah = (u16*)carve((size_t)1024 * K2 * 2);
  u16* wt2al = (u16*)carve((size_t)1024 * K2 * 2);
  u16* wt1bh = (u16*)carve((size_t)1024 * K1 * 2);
  u16* wt1bl = (u16*)carve((size_t)1024 * K1 * 2);
  u16* wt2bh = (u16*)carve((size_t)1024 * K2 * 2);
  u16* wt2bl = (u16*)carve((size_t)1024 * K2 * 2);

  size_t fixed = align256(off);
  const long long per_row = (long long)K1*4 + 8192 + 64;   // feats + h1(a,b) + partials
  long long avail = (long long)ws_size - (long long)fixed - 8192;
  long long rmax = avail > 0 ? avail / per_row : 0;
  int R = (int)((rmax / 128) * 128);
  if (R > B) R = B;
  if (R < 128) R = 128;

  u16* fh   = (u16*)carve((size_t)R * K1 * 2);
  u16* fl   = (u16*)carve((size_t)R * K1 * 2);
  u16* h1ah = (u16*)carve((size_t)R * 1024 * 2);
  u16* h1al = (u16*)carve((size_t)R * 1024 * 2);
  u16* h1bh = (u16*)carve((size_t)R * 1024 * 2);
  u16* h1bl = (u16*)carve((size_t)R * 1024 * 2);
  float* pa = (float*)carve((size_t)8 * R * 4);
  float* pb = (float*)carve((size_t)8 * R * 4);

  wconv_kernel<<<dim3(K1/32, 32), 256, 0, stream>>>(W1a, wt1ah, wt1al, 729,  K1);
  wconv_kernel<<<dim3(K2/32, 32), 256, 0, stream>>>(W2a, wt2ah, wt2al, 1024, K2);
  wconv_kernel<<<dim3(K1/32, 32), 256, 0, stream>>>(W1b, wt1bh, wt1bl, 729,  K1);
  wconv_kernel<<<dim3(K2/32, 32), 256, 0, stream>>>(W2b, wt2bh, wt2bl, 1024, K2);

  for (int row0 = 0; row0 < B; row0 += R){
    int Rc = B - row0; if (Rc > R) Rc = R;
    int MB = Rc / 128;
    feats_kernel<<<Rc/8, 256, 0, stream>>>(x, fh, fl, row0);
    gemm_k<0><<<dim3(16*MB), 256, 0, stream>>>(
        fh, fl, fh, fl,
        wt1ah, wt1al, wt1bh, wt1bl,
        b1a, b1b,
        h1ah, h1al, h1bh, h1bl,
        nullptr, nullptr, nullptr, nullptr, 0, K1);
    gemm_k<1><<<dim3(16*MB), 256, 0, stream>>>(
        h1ah, h1al, h1bh, h1bl,
        wt2ah, wt2al, wt2bh, wt2bl,
        b2a, b2b,
        nullptr, nullptr, nullptr, nullptr,
        W3a, W3b, pa, pb, R, K2);
    finalize_kernel<<<(Rc + 255)/256, 256, 0, stream>>>(pa, pb, R, b3a, Wfa, b3b, Wfb,
                                                        out, row0, Rc);
  }
}